// Round 2
// baseline (1521.551 us; speedup 1.0000x reference)
//
#include <hip/hip_runtime.h>
#include <hip/hip_bf16.h>
#include <cstdint>
#include <cstddef>

// Problem constants (DeBERTa-v2 attention, B=4,S=1024,H=1024,nH=16,d=64)
#define BB 4
#define SS 1024
#define HH 1024
#define NH 16
#define DD 64
#define SPANC 256
#define SPAN2 512

static constexpr float INV_SCALE = 0.07216878364870323f; // 1/sqrt(64*3)

// ---------------- relative-position bucket tables ----------------
// Faithful reproduction of reference make_log_bucket_position (incl. its
// quirks: bucket=127 for |rel|<128, bucket=+128 at rel=+-128).
__device__ __forceinline__ int log_bucket(int rel) {
  const int mid = 128;
  int ap = (rel < mid && rel > -mid) ? (mid - 1) : (rel < 0 ? -rel : rel);
  float logp = ceilf(logf((float)ap / 128.f) / logf(511.f / 128.f) * 127.f) + 128.f;
  float sgn = (rel > 0) ? 1.f : ((rel < 0) ? -1.f : 0.f);
  return (ap <= mid) ? ap : (int)(logp * sgn);
}

__global__ __launch_bounds__(256) void build_tables_k(int* __restrict__ ctab,
                                                      int* __restrict__ ptab) {
  int t = blockIdx.x * 256 + threadIdx.x;
  if (t >= 2047) return;
  int delta = t - 1023;  // delta = q - k
  int ci = log_bucket(delta) + SPANC;
  ci = ci < 0 ? 0 : (ci > SPAN2 - 1 ? SPAN2 - 1 : ci);
  int pi = -log_bucket(-delta) + SPANC;
  pi = pi < 0 ? 0 : (pi > SPAN2 - 1 ? SPAN2 - 1 : pi);
  ctab[t] = ci;
  ptab[t] = pi;
}

// ---------------- generic fp32 GEMM + bias: C[M,N] = A[M,K]@W[K,N] + b ----------------
__global__ __launch_bounds__(256) void gemm_bias_k(const float* __restrict__ A,
                                                   const float* __restrict__ W,
                                                   const float* __restrict__ bias,
                                                   float* __restrict__ C,
                                                   int M, int K, int N) {
  __shared__ float As[16][64];   // [k][m]
  __shared__ float Ws[16][68];   // [k][n]
  const int n0 = blockIdx.x * 64;
  const int m0 = blockIdx.y * 64;
  const int tid = threadIdx.x;
  const int tx = tid & 15, ty = tid >> 4;
  const int lr = tid >> 2, lc = (tid & 3) * 4;
  const int wr = tid >> 4, wc = (tid & 15) * 4;

  float acc[4][4] = {};
  for (int k0 = 0; k0 < K; k0 += 16) {
    __syncthreads();
    float4 a = *(const float4*)&A[(size_t)(m0 + lr) * K + k0 + lc];
    As[lc + 0][lr] = a.x; As[lc + 1][lr] = a.y; As[lc + 2][lr] = a.z; As[lc + 3][lr] = a.w;
    *(float4*)&Ws[wr][wc] = *(const float4*)&W[(size_t)(k0 + wr) * N + n0 + wc];
    __syncthreads();
#pragma unroll
    for (int kk = 0; kk < 16; ++kk) {
      float4 av = *(const float4*)&As[kk][ty * 4];
      float4 wv = *(const float4*)&Ws[kk][tx * 4];
      const float ar[4] = {av.x, av.y, av.z, av.w};
      const float wr2[4] = {wv.x, wv.y, wv.z, wv.w};
#pragma unroll
      for (int i = 0; i < 4; ++i)
#pragma unroll
        for (int j = 0; j < 4; ++j) acc[i][j] += ar[i] * wr2[j];
    }
  }
#pragma unroll
  for (int i = 0; i < 4; ++i) {
    const int m = m0 + ty * 4 + i;
#pragma unroll
    for (int j = 0; j < 4; ++j) {
      const int n = n0 + tx * 4 + j;
      C[(size_t)m * N + n] = acc[i][j] + bias[n];
    }
  }
}

// ---------------- batched NT GEMM: out[z,q,p] = sum_j In[b,q,h*64+j]*posk[p,h*64+j] ----------------
// bh = bh0 + blockIdx.z identifies (b,h); output indexed by LOCAL z (chunked buffer).
__global__ __launch_bounds__(256) void posatt_k(const float* __restrict__ In,
                                                const float* __restrict__ posk,
                                                __hip_bfloat16* __restrict__ outp,
                                                int bh0) {
  __shared__ float As[64][65];
  __shared__ float Bs[64][65];
  const int p0 = blockIdx.x * 64;
  const int q0 = blockIdx.y * 64;
  const int zl = blockIdx.z;
  const int bh = bh0 + zl;
  const int b = bh >> 4, h = bh & 15;
  const int tid = threadIdx.x;
  const int tx = tid & 15, ty = tid >> 4;

  const float* Ab = In + (size_t)b * SS * HH + (size_t)h * DD;
  const float* Bb = posk + (size_t)h * DD;
  const int lr = tid >> 2, lc0 = (tid & 3) * 16;
#pragma unroll
  for (int u = 0; u < 16; u += 4) {
    float4 a = *(const float4*)&Ab[(size_t)(q0 + lr) * HH + lc0 + u];
    As[lr][lc0 + u] = a.x; As[lr][lc0 + u + 1] = a.y;
    As[lr][lc0 + u + 2] = a.z; As[lr][lc0 + u + 3] = a.w;
    float4 bb = *(const float4*)&Bb[(size_t)(p0 + lr) * HH + lc0 + u];
    Bs[lr][lc0 + u] = bb.x; Bs[lr][lc0 + u + 1] = bb.y;
    Bs[lr][lc0 + u + 2] = bb.z; Bs[lr][lc0 + u + 3] = bb.w;
  }
  __syncthreads();
  float acc[4][4] = {};
#pragma unroll 8
  for (int c = 0; c < 64; ++c) {
    float ar[4], br[4];
#pragma unroll
    for (int i = 0; i < 4; ++i) ar[i] = As[ty * 4 + i][c];
#pragma unroll
    for (int j = 0; j < 4; ++j) br[j] = Bs[tx * 4 + j][c];
#pragma unroll
    for (int i = 0; i < 4; ++i)
#pragma unroll
      for (int j = 0; j < 4; ++j) acc[i][j] += ar[i] * br[j];
  }
  __hip_bfloat16* ob = outp + ((size_t)zl * SS + q0) * SPAN2 + p0;
#pragma unroll
  for (int i = 0; i < 4; ++i)
#pragma unroll
    for (int j = 0; j < 4; ++j)
      ob[(size_t)(ty * 4 + i) * SPAN2 + tx * 4 + j] = __float2bfloat16(acc[i][j]);
}

// ---------------- flash attention with disentangled bias ----------------
__global__ __launch_bounds__(256) void flash_attn_k(
    const float* __restrict__ Q, const float* __restrict__ K, const float* __restrict__ V,
    const __hip_bfloat16* __restrict__ c2p, const __hip_bfloat16* __restrict__ p2c,
    const int* __restrict__ ctab, const int* __restrict__ ptab,
    float* __restrict__ ctx, int bh0) {
  __shared__ float Qs[64][64];
  __shared__ float Ks[64][65];
  __shared__ float Vs[64][65];
  __shared__ __hip_bfloat16 Ps[64][64];

  const int qt = blockIdx.x;
  const int zl = blockIdx.y;           // local bh within chunk
  const int bh = bh0 + zl;
  const int b = bh >> 4, h = bh & 15;
  const int q0 = qt * 64;
  const int tid = threadIdx.x;
  const int lane = tid & 63;
  const int wave = tid >> 6;

  const size_t headoff = (size_t)b * SS * HH + (size_t)h * DD;
  const float* Qb = Q + headoff;
  const float* Kb = K + headoff;
  const float* Vb = V + headoff;

  {
    const int r = tid >> 2, c0 = (tid & 3) * 16;
#pragma unroll
    for (int u = 0; u < 16; u += 4) {
      float4 qv = *(const float4*)&Qb[(size_t)(q0 + r) * HH + c0 + u];
      Qs[r][c0 + u] = qv.x; Qs[r][c0 + u + 1] = qv.y;
      Qs[r][c0 + u + 2] = qv.z; Qs[r][c0 + u + 3] = qv.w;
    }
  }

  float m_i[16], l_i[16], acc[16];
#pragma unroll
  for (int i = 0; i < 16; ++i) { m_i[i] = -1e30f; l_i[i] = 0.f; acc[i] = 0.f; }

  const size_t z_s = (size_t)zl * SS;

  for (int kt = 0; kt < 16; ++kt) {
    const int k0 = kt * 64;
    __syncthreads();
    {
      const int r = tid >> 2, c0 = (tid & 3) * 16;
#pragma unroll
      for (int u = 0; u < 16; u += 4) {
        float4 kv = *(const float4*)&Kb[(size_t)(k0 + r) * HH + c0 + u];
        Ks[r][c0 + u] = kv.x; Ks[r][c0 + u + 1] = kv.y;
        Ks[r][c0 + u + 2] = kv.z; Ks[r][c0 + u + 3] = kv.w;
        float4 vv = *(const float4*)&Vb[(size_t)(k0 + r) * HH + c0 + u];
        Vs[r][c0 + u] = vv.x; Vs[r][c0 + u + 1] = vv.y;
        Vs[r][c0 + u + 2] = vv.z; Vs[r][c0 + u + 3] = vv.w;
      }
    }
    __syncthreads();

    const int kg = k0 + lane;
#pragma unroll 1
    for (int rr = 0; rr < 16; ++rr) {
      const int row = wave * 16 + rr;
      const int qg = q0 + row;
      float s = 0.f;
#pragma unroll
      for (int c = 0; c < 64; c += 4) {
        float4 qv = *(const float4*)&Qs[row][c];
        s += qv.x * Ks[lane][c] + qv.y * Ks[lane][c + 1] +
             qv.z * Ks[lane][c + 2] + qv.w * Ks[lane][c + 3];
      }
      const int dl = qg - kg + 1023;
      const float bias = __bfloat162float(c2p[(z_s + qg) * SPAN2 + ctab[dl]]) +
                         __bfloat162float(p2c[(z_s + kg) * SPAN2 + ptab[dl]]);
      s = (s + bias) * INV_SCALE;
      float mx = s;
#pragma unroll
      for (int off = 32; off; off >>= 1) mx = fmaxf(mx, __shfl_xor(mx, off, 64));
      const float mnew = fmaxf(m_i[rr], mx);
      const float p = __expf(s - mnew);
      float ps = p;
#pragma unroll
      for (int off = 32; off; off >>= 1) ps += __shfl_xor(ps, off, 64);
      const float alpha = __expf(m_i[rr] - mnew);
      l_i[rr] = l_i[rr] * alpha + ps;
      acc[rr] *= alpha;
      m_i[rr] = mnew;
      Ps[row][lane] = __float2bfloat16(p);
    }
    __syncthreads();
#pragma unroll 1
    for (int rr = 0; rr < 16; ++rr) {
      const int row = wave * 16 + rr;
      float a = 0.f;
#pragma unroll
      for (int c = 0; c < 64; c += 2) {
        a += __bfloat162float(Ps[row][c]) * Vs[c][lane] +
             __bfloat162float(Ps[row][c + 1]) * Vs[c + 1][lane];
      }
      acc[rr] += a;
    }
  }

#pragma unroll
  for (int rr = 0; rr < 16; ++rr) {
    const int row = wave * 16 + rr;
    ctx[(size_t)(b * SS + q0 + row) * HH + h * DD + lane] = acc[rr] / l_i[rr];
  }
}

// ---------------- residual + LayerNorm epilogue ----------------
__global__ __launch_bounds__(256) void out_ln_k(const float* __restrict__ proj,
                                                const float* __restrict__ resid,
                                                const float* __restrict__ gamma,
                                                const float* __restrict__ beta,
                                                float* __restrict__ out) {
  const int row = blockIdx.x;
  const int tid = threadIdx.x;
  const size_t base = (size_t)row * HH;
  float v[4];
  float s = 0.f;
#pragma unroll
  for (int u = 0; u < 4; ++u) {
    const int c = tid + u * 256;
    v[u] = proj[base + c] + resid[base + c];
    s += v[u];
  }
  __shared__ float red[8];
#pragma unroll
  for (int off = 32; off; off >>= 1) s += __shfl_xor(s, off, 64);
  if ((tid & 63) == 0) red[tid >> 6] = s;
  __syncthreads();
  const float mu = (red[0] + red[1] + red[2] + red[3]) * (1.f / HH);
  float s2 = 0.f;
#pragma unroll
  for (int u = 0; u < 4; ++u) { const float d = v[u] - mu; s2 += d * d; }
#pragma unroll
  for (int off = 32; off; off >>= 1) s2 += __shfl_xor(s2, off, 64);
  if ((tid & 63) == 0) red[4 + (tid >> 6)] = s2;
  __syncthreads();
  const float var = (red[4] + red[5] + red[6] + red[7]) * (1.f / HH);
  const float rs = rsqrtf(var + 1e-7f);
#pragma unroll
  for (int u = 0; u < 4; ++u) {
    const int c = tid + u * 256;
    out[base + c] = (v[u] - mu) * rs * gamma[c] + beta[c];
  }
}

extern "C" void kernel_launch(void* const* d_in, const int* in_sizes, int n_in,
                              void* d_out, int out_size, void* d_ws, size_t ws_size,
                              hipStream_t stream) {
  (void)in_sizes; (void)n_in; (void)out_size;
  const float* hs  = (const float*)d_in[0];
  const float* rel = (const float*)d_in[2];  // d_in[1] attention_mask unused (faithful)
  const float* Wq  = (const float*)d_in[3];
  const float* bq  = (const float*)d_in[4];
  const float* Wk  = (const float*)d_in[5];
  const float* bk  = (const float*)d_in[6];
  const float* Wv  = (const float*)d_in[7];
  const float* bv  = (const float*)d_in[8];
  const float* Wo  = (const float*)d_in[9];
  const float* bo  = (const float*)d_in[10];
  const float* lng = (const float*)d_in[11];
  const float* lnb = (const float*)d_in[12];
  float* out = (float*)d_out;

  // ---- tight workspace packing (sizes in bytes) ----
  const size_t SZ_QKV = (size_t)4096 * 1024 * 4;   // 16 MiB each
  char* ws = (char*)d_ws;
  float* Qb   = (float*)(ws);
  float* Kb   = (float*)(ws + SZ_QKV);
  float* Vb   = (float*)(ws + 2 * SZ_QKV);
  float* ctxb = (float*)(ws + 3 * SZ_QKV);
  float* posk = (float*)(ws + 4 * SZ_QKV);                    // 512*1024*4 = 2 MiB
  int*   ctab = (int*)(ws + 4 * SZ_QKV + 2097152);            // 8 KiB
  int*   ptab = ctab + 2048;                                   // 8 KiB
  char*  bias_base = ws + 4 * SZ_QKV + 2097152 + 16384;
  const size_t perbh = (size_t)SS * SPAN2 * 2;                // 1 MiB per bh (bf16)

  // Largest power-of-two chunk of the 64 (b,h) pairs whose two bias buffers fit.
  const size_t fixed = (size_t)(bias_base - ws);
  int chunk = 64;
  while (chunk > 1 && fixed + 2 * (size_t)chunk * perbh > ws_size) chunk >>= 1;
  __hip_bfloat16* c2p = (__hip_bfloat16*)bias_base;
  __hip_bfloat16* p2c = (__hip_bfloat16*)(bias_base + (size_t)chunk * perbh);

  build_tables_k<<<dim3(8), 256, 0, stream>>>(ctab, ptab);

  const dim3 gQKV(16, 64);  // N/64, M/64
  gemm_bias_k<<<gQKV, 256, 0, stream>>>(hs, Wq, bq, Qb, 4096, 1024, 1024);
  gemm_bias_k<<<gQKV, 256, 0, stream>>>(hs, Wk, bk, Kb, 4096, 1024, 1024);
  gemm_bias_k<<<gQKV, 256, 0, stream>>>(hs, Wv, bv, Vb, 4096, 1024, 1024);
  gemm_bias_k<<<dim3(16, 8), 256, 0, stream>>>(rel, Wk, bk, posk, 512, 1024, 1024);

  for (int bh0 = 0; bh0 < 64; bh0 += chunk) {
    posatt_k<<<dim3(8, 16, chunk), 256, 0, stream>>>(Qb, posk, c2p, bh0);
    posatt_k<<<dim3(8, 16, chunk), 256, 0, stream>>>(Kb, posk, p2c, bh0);
    flash_attn_k<<<dim3(16, chunk), 256, 0, stream>>>(Qb, Kb, Vb, c2p, p2c,
                                                      ctab, ptab, ctxb, bh0);
  }

  // out-proj reuses Qb as scratch (Q dead after flash)
  gemm_bias_k<<<gQKV, 256, 0, stream>>>(ctxb, Wo, bo, Qb, 4096, 1024, 1024);
  out_ln_k<<<4096, 256, 0, stream>>>(Qb, hs, lng, lnb, out);
}

// Round 3
// 349.673 us; speedup vs baseline: 4.3514x; 4.3514x over previous
//
#include <hip/hip_runtime.h>
#include <hip/hip_bf16.h>
#include <cstdint>
#include <cstddef>

#define BB 4
#define SS 1024
#define HH 1024
#define NH 16
#define DD 64
#define SPANC 256
#define SPAN2 512

static constexpr float INV_SCALE = 0.07216878364870323f; // 1/sqrt(64*3)

typedef unsigned short ush;
typedef short bf16x8 __attribute__((ext_vector_type(8)));
typedef unsigned short ushx8 __attribute__((ext_vector_type(8)));
typedef float f32x4 __attribute__((ext_vector_type(4)));

__device__ __forceinline__ ush f2bf(float f) {
  unsigned int u = __float_as_uint(f);
  unsigned int r = (u + 0x7fffu + ((u >> 16) & 1u)) >> 16;   // RNE
  return (ush)r;
}
__device__ __forceinline__ float bf2f(ush h) {
  return __uint_as_float(((unsigned int)h) << 16);
}

// ---------------- relative-position bucket tables ----------------
__device__ __forceinline__ int log_bucket(int rel) {
  const int mid = 128;
  int ap = (rel < mid && rel > -mid) ? (mid - 1) : (rel < 0 ? -rel : rel);
  float logp = ceilf(logf((float)ap / 128.f) / logf(511.f / 128.f) * 127.f) + 128.f;
  float sgn = (rel > 0) ? 1.f : ((rel < 0) ? -1.f : 0.f);
  return (ap <= mid) ? ap : (int)(logp * sgn);
}

__global__ __launch_bounds__(256) void build_tables_k(int* __restrict__ ctab,
                                                      int* __restrict__ ptab) {
  int t = blockIdx.x * 256 + threadIdx.x;
  if (t >= 2047) return;
  int delta = t - 1023;
  int ci = log_bucket(delta) + SPANC;
  ci = ci < 0 ? 0 : (ci > SPAN2 - 1 ? SPAN2 - 1 : ci);
  int pi = -log_bucket(-delta) + SPANC;
  pi = pi < 0 ? 0 : (pi > SPAN2 - 1 ? SPAN2 - 1 : pi);
  ctab[t] = ci;
  ptab[t] = pi;
}

// ---------------- f32 -> bf16 elementwise (n % 1024 == 0) ----------------
__global__ __launch_bounds__(256) void cvt_bf16_k(const float* __restrict__ in,
                                                  ush* __restrict__ out) {
  const int i = (blockIdx.x * 256 + threadIdx.x) * 4;
  float4 v = *(const float4*)&in[i];
  ushort4 o;
  o.x = f2bf(v.x); o.y = f2bf(v.y); o.z = f2bf(v.z); o.w = f2bf(v.w);
  *(ushort4*)&out[i] = o;
}

// ---------------- W[1024][1024] f32 -> Wt[1024][1024] bf16 (transposed) ----------------
__global__ __launch_bounds__(256) void transpose_cvt_k(const float* __restrict__ W,
                                                       ush* __restrict__ Wt) {
  __shared__ float Ls[64][68];
  const int k0 = blockIdx.x * 64;
  const int n0 = blockIdx.y * 64;
  const int t = threadIdx.x;
#pragma unroll
  for (int rr = 0; rr < 4; ++rr) {
    const int r = (t >> 4) + rr * 16, c = (t & 15) * 4;
    float4 v = *(const float4*)&W[(size_t)(k0 + r) * 1024 + n0 + c];
    Ls[r][c] = v.x; Ls[r][c + 1] = v.y; Ls[r][c + 2] = v.z; Ls[r][c + 3] = v.w;
  }
  __syncthreads();
#pragma unroll
  for (int rr = 0; rr < 4; ++rr) {
    const int r = (t >> 4) + rr * 16, c = (t & 15) * 4;  // r: n-dim, c: k-dim
    ushort4 o;
    o.x = f2bf(Ls[c + 0][r]); o.y = f2bf(Ls[c + 1][r]);
    o.z = f2bf(Ls[c + 2][r]); o.w = f2bf(Ls[c + 3][r]);
    *(ushort4*)&Wt[(size_t)(n0 + r) * 1024 + k0 + c] = o;
  }
}

// ---------------- bf16 MFMA NT-GEMM: C[M,N] = A[M,K] @ Bt[N,K]^T + bias ----------------
// 128x128 tile, BK=64, 256 threads (4 waves, 2x2), each wave 64x64 out.
template <typename OT>
__global__ __launch_bounds__(256) void gemm_bt_k(const ush* __restrict__ A,
                                                 const ush* __restrict__ Bt,
                                                 const float* __restrict__ bias,
                                                 OT* __restrict__ C,
                                                 int M, int N, int K) {
  __shared__ ush Asl[128][72];
  __shared__ ush Btl[128][72];
  const int n0 = blockIdx.x * 128;
  const int m0 = blockIdx.y * 128;
  const int tid = threadIdx.x;
  const int lane = tid & 63, w = tid >> 6;
  const int wm = (w >> 1) * 64, wn = (w & 1) * 64;
  const int ln = lane & 15, hi = lane >> 4;

  f32x4 acc[4][4] = {};
  for (int k0 = 0; k0 < K; k0 += 64) {
    __syncthreads();
#pragma unroll
    for (int rr = 0; rr < 4; ++rr) {
      const int r = (tid >> 3) + rr * 32, c = (tid & 7) * 8;
      *(ushx8*)&Asl[r][c] = *(const ushx8*)&A[(size_t)(m0 + r) * K + k0 + c];
      *(ushx8*)&Btl[r][c] = *(const ushx8*)&Bt[(size_t)(n0 + r) * K + k0 + c];
    }
    __syncthreads();
    bf16x8 af[4][2], bf[4][2];
#pragma unroll
    for (int mi = 0; mi < 4; ++mi)
#pragma unroll
      for (int ks = 0; ks < 2; ++ks)
        af[mi][ks] = *(const bf16x8*)&Asl[wm + mi * 16 + ln][ks * 32 + hi * 8];
#pragma unroll
    for (int ni = 0; ni < 4; ++ni)
#pragma unroll
      for (int ks = 0; ks < 2; ++ks)
        bf[ni][ks] = *(const bf16x8*)&Btl[wn + ni * 16 + ln][ks * 32 + hi * 8];
#pragma unroll
    for (int mi = 0; mi < 4; ++mi)
#pragma unroll
      for (int ni = 0; ni < 4; ++ni)
#pragma unroll
        for (int ks = 0; ks < 2; ++ks)
          acc[mi][ni] = __builtin_amdgcn_mfma_f32_16x16x32_bf16(
              af[mi][ks], bf[ni][ks], acc[mi][ni], 0, 0, 0);
  }
#pragma unroll
  for (int mi = 0; mi < 4; ++mi)
#pragma unroll
    for (int ni = 0; ni < 4; ++ni)
#pragma unroll
      for (int i = 0; i < 4; ++i) {
        const int grow = m0 + wm + mi * 16 + hi * 4 + i;
        const int gcol = n0 + wn + ni * 16 + ln;
        const float v = acc[mi][ni][i] + bias[gcol];
        if (sizeof(OT) == 2) {
          ((ush*)C)[(size_t)grow * N + gcol] = f2bf(v);
        } else {
          ((float*)C)[(size_t)grow * N + gcol] = v;
        }
      }
}

// ---------------- posatt MFMA: out[zl,q,p] = In[b,q,h*64+:64] . posk[p,h*64+:64] ----------------
__global__ __launch_bounds__(256) void posatt_k(const ush* __restrict__ In,
                                                const ush* __restrict__ posk,
                                                ush* __restrict__ outp, int bh0) {
  __shared__ ush Al[64][72];
  __shared__ ush Bl[64][72];
  const int p0 = blockIdx.x * 64;
  const int q0 = blockIdx.y * 64;
  const int zl = blockIdx.z;
  const int bh = bh0 + zl;
  const int b = bh >> 4, h = bh & 15;
  const int tid = threadIdx.x;
  const int lane = tid & 63, w = tid >> 6;
  const int ln = lane & 15, hi = lane >> 4;

#pragma unroll
  for (int rr = 0; rr < 2; ++rr) {
    const int r = (tid >> 3) + rr * 32, c = (tid & 7) * 8;
    *(ushx8*)&Al[r][c] = *(const ushx8*)&In[(size_t)(b * SS + q0 + r) * HH + h * DD + c];
    *(ushx8*)&Bl[r][c] = *(const ushx8*)&posk[(size_t)(p0 + r) * HH + h * DD + c];
  }
  __syncthreads();

  bf16x8 aq[2];
#pragma unroll
  for (int ks = 0; ks < 2; ++ks)
    aq[ks] = *(const bf16x8*)&Al[w * 16 + ln][ks * 32 + hi * 8];
  f32x4 acc[4] = {};
#pragma unroll
  for (int ni = 0; ni < 4; ++ni)
#pragma unroll
    for (int ks = 0; ks < 2; ++ks) {
      bf16x8 bp = *(const bf16x8*)&Bl[ni * 16 + ln][ks * 32 + hi * 8];
      acc[ni] = __builtin_amdgcn_mfma_f32_16x16x32_bf16(aq[ks], bp, acc[ni], 0, 0, 0);
    }
#pragma unroll
  for (int ni = 0; ni < 4; ++ni)
#pragma unroll
    for (int i = 0; i < 4; ++i) {
      const int orow = q0 + w * 16 + hi * 4 + i;
      const int ocol = p0 + ni * 16 + ln;
      outp[((size_t)zl * SS + orow) * SPAN2 + ocol] = f2bf(acc[ni][i]);
    }
}

// ---------------- MFMA flash attention with disentangled bias ----------------
__global__ __launch_bounds__(256) void flash_attn_k(
    const ush* __restrict__ Q, const ush* __restrict__ K, const ush* __restrict__ V,
    const ush* __restrict__ c2p, const ush* __restrict__ p2c,
    const int* __restrict__ ctab, const int* __restrict__ ptab,
    ush* __restrict__ ctx, int bh0) {
  __shared__ ush Kl[64][72];
  __shared__ ush Vt[64][72];   // transposed: Vt[d][k]
  __shared__ ush Pl[64][72];   // also used to stage Q once
  __shared__ int ctabs[1088];
  __shared__ int ptabs[1088];

  const int q0 = blockIdx.x * 64;
  const int zl = blockIdx.y;
  const int bh = bh0 + zl;
  const int b = bh >> 4, h = bh & 15;
  const int tid = threadIdx.x;
  const int lane = tid & 63, w = tid >> 6;
  const int ln = lane & 15, hi = lane >> 4;

  for (int i2 = tid; i2 < 1087; i2 += 256) {
    ctabs[i2] = ctab[q0 + i2];
    ptabs[i2] = ptab[q0 + i2];
  }
  // stage Q tile into Pl
#pragma unroll
  for (int rr = 0; rr < 2; ++rr) {
    const int r = (tid >> 3) + rr * 32, c = (tid & 7) * 8;
    *(ushx8*)&Pl[r][c] = *(const ushx8*)&Q[(size_t)(b * SS + q0 + r) * HH + h * DD + c];
  }
  __syncthreads();
  bf16x8 aq[2];
#pragma unroll
  for (int ks = 0; ks < 2; ++ks)
    aq[ks] = *(const bf16x8*)&Pl[w * 16 + ln][ks * 32 + hi * 8];
  __syncthreads();

  float m_i[4], l_i[4];
  f32x4 Oa[4] = {};
#pragma unroll
  for (int i = 0; i < 4; ++i) { m_i[i] = -1e30f; l_i[i] = 0.f; }

  const size_t zq = (size_t)zl * SS;

  for (int kt = 0; kt < 16; ++kt) {
    const int k0 = kt * 64;
    __syncthreads();  // protect Kl/Vt restage vs previous PV reads
    {
      // K tile, row-major
#pragma unroll
      for (int rr = 0; rr < 2; ++rr) {
        const int r = (tid >> 3) + rr * 32, c = (tid & 7) * 8;
        *(ushx8*)&Kl[r][c] = *(const ushx8*)&K[(size_t)(b * SS + k0 + r) * HH + h * DD + c];
      }
      // V tile, transposed into Vt[d][k]
      const int kp = tid & 31, dg = (tid >> 5) * 8;
      ushx8 v0 = *(const ushx8*)&V[(size_t)(b * SS + k0 + 2 * kp) * HH + h * DD + dg];
      ushx8 v1 = *(const ushx8*)&V[(size_t)(b * SS + k0 + 2 * kp + 1) * HH + h * DD + dg];
#pragma unroll
      for (int j = 0; j < 8; ++j) {
        unsigned int pk = (unsigned int)v0[j] | ((unsigned int)v1[j] << 16);
        *(unsigned int*)&Vt[dg + j][2 * kp] = pk;
      }
    }
    __syncthreads();

    // QK^T
    f32x4 s4[4] = {};
#pragma unroll
    for (int ni = 0; ni < 4; ++ni)
#pragma unroll
      for (int ks = 0; ks < 2; ++ks) {
        bf16x8 bk = *(const bf16x8*)&Kl[ni * 16 + ln][ks * 32 + hi * 8];
        s4[ni] = __builtin_amdgcn_mfma_f32_16x16x32_bf16(aq[ks], bk, s4[ni], 0, 0, 0);
      }

    // bias gathers
#pragma unroll
    for (int ni = 0; ni < 4; ++ni)
#pragma unroll
      for (int i = 0; i < 4; ++i) {
        const int qr = w * 16 + hi * 4 + i;      // q row within block
        const int qg = q0 + qr;
        const int kg = k0 + ni * 16 + ln;
        const int idx = qr - kg + 1023;          // dl - q0, in [0,1086]
        const float bias = bf2f(c2p[(zq + qg) * SPAN2 + ctabs[idx]]) +
                           bf2f(p2c[(zq + kg) * SPAN2 + ptabs[idx]]);
        s4[ni][i] = (s4[ni][i] + bias) * INV_SCALE;
      }

    // online softmax (rows live across 16-lane groups)
#pragma unroll
    for (int i = 0; i < 4; ++i) {
      float mx = fmaxf(fmaxf(s4[0][i], s4[1][i]), fmaxf(s4[2][i], s4[3][i]));
      mx = fmaxf(mx, __shfl_xor(mx, 1, 64));
      mx = fmaxf(mx, __shfl_xor(mx, 2, 64));
      mx = fmaxf(mx, __shfl_xor(mx, 4, 64));
      mx = fmaxf(mx, __shfl_xor(mx, 8, 64));
      const float mnew = fmaxf(m_i[i], mx);
      const float al = __expf(m_i[i] - mnew);
      m_i[i] = mnew;
      float ps = 0.f;
#pragma unroll
      for (int ni = 0; ni < 4; ++ni) {
        const float p = __expf(s4[ni][i] - mnew);
        s4[ni][i] = p;
        ps += p;
      }
      ps += __shfl_xor(ps, 1, 64);
      ps += __shfl_xor(ps, 2, 64);
      ps += __shfl_xor(ps, 4, 64);
      ps += __shfl_xor(ps, 8, 64);
      l_i[i] = l_i[i] * al + ps;
#pragma unroll
      for (int ni = 0; ni < 4; ++ni) Oa[ni][i] *= al;
    }

    // P -> LDS bf16
#pragma unroll
    for (int ni = 0; ni < 4; ++ni)
#pragma unroll
      for (int i = 0; i < 4; ++i)
        Pl[w * 16 + hi * 4 + i][ni * 16 + ln] = f2bf(s4[ni][i]);
    __syncthreads();

    // PV
    bf16x8 ap[2];
#pragma unroll
    for (int ks = 0; ks < 2; ++ks)
      ap[ks] = *(const bf16x8*)&Pl[w * 16 + ln][ks * 32 + hi * 8];
#pragma unroll
    for (int ni = 0; ni < 4; ++ni)
#pragma unroll
      for (int ks = 0; ks < 2; ++ks) {
        bf16x8 bv = *(const bf16x8*)&Vt[ni * 16 + ln][ks * 32 + hi * 8];
        Oa[ni] = __builtin_amdgcn_mfma_f32_16x16x32_bf16(ap[ks], bv, Oa[ni], 0, 0, 0);
      }
  }

  float inv_l[4];
#pragma unroll
  for (int i = 0; i < 4; ++i) inv_l[i] = 1.f / l_i[i];
#pragma unroll
  for (int ni = 0; ni < 4; ++ni)
#pragma unroll
    for (int i = 0; i < 4; ++i) {
      const int qg = q0 + w * 16 + hi * 4 + i;
      ctx[(size_t)(b * SS + qg) * HH + h * DD + ni * 16 + ln] = f2bf(Oa[ni][i] * inv_l[i]);
    }
}

// ---------------- residual + LayerNorm epilogue ----------------
__global__ __launch_bounds__(256) void out_ln_k(const float* __restrict__ proj,
                                                const float* __restrict__ resid,
                                                const float* __restrict__ gamma,
                                                const float* __restrict__ beta,
                                                float* __restrict__ out) {
  const int row = blockIdx.x;
  const int tid = threadIdx.x;
  const size_t base = (size_t)row * HH;
  float v[4];
  float s = 0.f;
#pragma unroll
  for (int u = 0; u < 4; ++u) {
    const int c = tid + u * 256;
    v[u] = proj[base + c] + resid[base + c];
    s += v[u];
  }
  __shared__ float red[8];
#pragma unroll
  for (int off = 32; off; off >>= 1) s += __shfl_xor(s, off, 64);
  if ((tid & 63) == 0) red[tid >> 6] = s;
  __syncthreads();
  const float mu = (red[0] + red[1] + red[2] + red[3]) * (1.f / HH);
  float s2 = 0.f;
#pragma unroll
  for (int u = 0; u < 4; ++u) { const float d = v[u] - mu; s2 += d * d; }
#pragma unroll
  for (int off = 32; off; off >>= 1) s2 += __shfl_xor(s2, off, 64);
  if ((tid & 63) == 0) red[4 + (tid >> 6)] = s2;
  __syncthreads();
  const float var = (red[4] + red[5] + red[6] + red[7]) * (1.f / HH);
  const float rs = rsqrtf(var + 1e-7f);
#pragma unroll
  for (int u = 0; u < 4; ++u) {
    const int c = tid + u * 256;
    out[base + c] = (v[u] - mu) * rs * gamma[c] + beta[c];
  }
}

extern "C" void kernel_launch(void* const* d_in, const int* in_sizes, int n_in,
                              void* d_out, int out_size, void* d_ws, size_t ws_size,
                              hipStream_t stream) {
  (void)in_sizes; (void)n_in; (void)out_size;
  const float* hs  = (const float*)d_in[0];
  const float* rel = (const float*)d_in[2];  // d_in[1] attention_mask unused (faithful)
  const float* Wq  = (const float*)d_in[3];
  const float* bq  = (const float*)d_in[4];
  const float* Wk  = (const float*)d_in[5];
  const float* bk  = (const float*)d_in[6];
  const float* Wv  = (const float*)d_in[7];
  const float* bv  = (const float*)d_in[8];
  const float* Wo  = (const float*)d_in[9];
  const float* bo  = (const float*)d_in[10];
  const float* lng = (const float*)d_in[11];
  const float* lnb = (const float*)d_in[12];
  float* out = (float*)d_out;

  // ---- workspace packing ----
  char* ws = (char*)d_ws;
  const size_t MB = 1024ull * 1024ull;
  ush*   hs_bf  = (ush*)(ws);                 //  8 MB [4096,1024]
  ush*   Q_bf   = (ush*)(ws + 8 * MB);        //  8 MB
  ush*   K_bf   = (ush*)(ws + 16 * MB);       //  8 MB
  ush*   V_bf   = (ush*)(ws + 24 * MB);       //  8 MB
  ush*   ctx_bf = (ush*)(ws + 32 * MB);       //  8 MB
  ush*   rel_bf = (ush*)(ws + 40 * MB);       //  1 MB [512,1024]
  ush*   posk_bf= (ush*)(ws + 41 * MB);       //  1 MB [512,1024]
  ush*   Wq_t   = (ush*)(ws + 42 * MB);       //  2 MB each, transposed bf16
  ush*   Wk_t   = (ush*)(ws + 44 * MB);
  ush*   Wv_t   = (ush*)(ws + 46 * MB);
  ush*   Wo_t   = (ush*)(ws + 48 * MB);
  float* proj   = (float*)(ws + 50 * MB);     // 16 MB [4096,1024] f32
  int*   ctab   = (int*)(ws + 66 * MB);       //  8 KB
  int*   ptab   = ctab + 2048;
  char*  bias_base = ws + 66 * MB + 16384;
  const size_t perbh = (size_t)SS * SPAN2 * 2;  // 1 MB per bh per buffer

  const size_t fixed = (size_t)(bias_base - ws);
  int chunk = 64;
  while (chunk > 1 && fixed + 2 * (size_t)chunk * perbh > ws_size) chunk >>= 1;
  ush* c2p = (ush*)bias_base;
  ush* p2c = (ush*)(bias_base + (size_t)chunk * perbh);

  build_tables_k<<<dim3(8), 256, 0, stream>>>(ctab, ptab);
  cvt_bf16_k<<<dim3(4096), 256, 0, stream>>>(hs, hs_bf);
  cvt_bf16_k<<<dim3(512), 256, 0, stream>>>(rel, rel_bf);
  transpose_cvt_k<<<dim3(16, 16), 256, 0, stream>>>(Wq, Wq_t);
  transpose_cvt_k<<<dim3(16, 16), 256, 0, stream>>>(Wk, Wk_t);
  transpose_cvt_k<<<dim3(16, 16), 256, 0, stream>>>(Wv, Wv_t);
  transpose_cvt_k<<<dim3(16, 16), 256, 0, stream>>>(Wo, Wo_t);

  gemm_bt_k<ush><<<dim3(8, 32), 256, 0, stream>>>(hs_bf, Wq_t, bq, Q_bf, 4096, 1024, 1024);
  gemm_bt_k<ush><<<dim3(8, 32), 256, 0, stream>>>(hs_bf, Wk_t, bk, K_bf, 4096, 1024, 1024);
  gemm_bt_k<ush><<<dim3(8, 32), 256, 0, stream>>>(hs_bf, Wv_t, bv, V_bf, 4096, 1024, 1024);
  gemm_bt_k<ush><<<dim3(8, 4), 256, 0, stream>>>(rel_bf, Wk_t, bk, posk_bf, 512, 1024, 1024);

  for (int bh0 = 0; bh0 < 64; bh0 += chunk) {
    posatt_k<<<dim3(8, 16, chunk), 256, 0, stream>>>(Q_bf, posk_bf, c2p, bh0);
    posatt_k<<<dim3(8, 16, chunk), 256, 0, stream>>>(K_bf, posk_bf, p2c, bh0);
    flash_attn_k<<<dim3(16, chunk), 256, 0, stream>>>(Q_bf, K_bf, V_bf, c2p, p2c,
                                                      ctab, ptab, ctx_bf, bh0);
  }

  gemm_bt_k<float><<<dim3(8, 32), 256, 0, stream>>>(ctx_bf, Wo_t, bo, proj, 4096, 1024, 1024);
  out_ln_k<<<4096, 256, 0, stream>>>(proj, hs, lng, lnb, out);
}

// Round 5
// 325.284 us; speedup vs baseline: 4.6776x; 1.0750x over previous
//
#include <hip/hip_runtime.h>
#include <hip/hip_bf16.h>
#include <cstdint>
#include <cstddef>

#define BB 4
#define SS 1024
#define HH 1024
#define NH 16
#define DD 64
#define SPANC 256
#define SPAN2 512

static constexpr float INV_SCALE = 0.07216878364870323f;            // 1/sqrt(64*3)
static constexpr float INV_SCALE_L2 = 0.07216878364870323f * 1.44269504088896f;

typedef unsigned short ush;
typedef short bf16x8 __attribute__((ext_vector_type(8)));
typedef unsigned short ushx8 __attribute__((ext_vector_type(8)));
typedef float f32x4 __attribute__((ext_vector_type(4)));

__device__ __forceinline__ float fast_exp2(float x) {
  float r;
  asm volatile("v_exp_f32 %0, %1" : "=v"(r) : "v"(x));  // v_exp_f32 computes 2^x
  return r;
}

__device__ __forceinline__ ush f2bf(float f) {
  unsigned int u = __float_as_uint(f);
  unsigned int r = (u + 0x7fffu + ((u >> 16) & 1u)) >> 16;   // RNE
  return (ush)r;
}
__device__ __forceinline__ float bf2f(ush h) {
  return __uint_as_float(((unsigned int)h) << 16);
}

// ---------------- relative-position bucket tables ----------------
__device__ __forceinline__ int log_bucket(int rel) {
  const int mid = 128;
  int ap = (rel < mid && rel > -mid) ? (mid - 1) : (rel < 0 ? -rel : rel);
  float logp = ceilf(logf((float)ap / 128.f) / logf(511.f / 128.f) * 127.f) + 128.f;
  float sgn = (rel > 0) ? 1.f : ((rel < 0) ? -1.f : 0.f);
  return (ap <= mid) ? ap : (int)(logp * sgn);
}

__global__ __launch_bounds__(256) void build_tables_k(int* __restrict__ ctab,
                                                      int* __restrict__ ptab) {
  int t = blockIdx.x * 256 + threadIdx.x;
  if (t >= 2047) return;
  int delta = t - 1023;
  int ci = log_bucket(delta) + SPANC;
  ci = ci < 0 ? 0 : (ci > SPAN2 - 1 ? SPAN2 - 1 : ci);
  int pi = -log_bucket(-delta) + SPANC;
  pi = pi < 0 ? 0 : (pi > SPAN2 - 1 ? SPAN2 - 1 : pi);
  ctab[t] = ci;
  ptab[t] = pi;
}

// ---------------- f32 -> bf16 elementwise (n % 1024 == 0) ----------------
__global__ __launch_bounds__(256) void cvt_bf16_k(const float* __restrict__ in,
                                                  ush* __restrict__ out) {
  const int i = (blockIdx.x * 256 + threadIdx.x) * 4;
  float4 v = *(const float4*)&in[i];
  ushort4 o;
  o.x = f2bf(v.x); o.y = f2bf(v.y); o.z = f2bf(v.z); o.w = f2bf(v.w);
  *(ushort4*)&out[i] = o;
}

// ---------------- W[1024][1024] f32 -> Wt[1024][1024] bf16 (transposed) ----------------
__global__ __launch_bounds__(256) void transpose_cvt_k(const float* __restrict__ W,
                                                       ush* __restrict__ Wt) {
  __shared__ float Ls[64][68];
  const int k0 = blockIdx.x * 64;
  const int n0 = blockIdx.y * 64;
  const int t = threadIdx.x;
#pragma unroll
  for (int rr = 0; rr < 4; ++rr) {
    const int r = (t >> 4) + rr * 16, c = (t & 15) * 4;
    float4 v = *(const float4*)&W[(size_t)(k0 + r) * 1024 + n0 + c];
    Ls[r][c] = v.x; Ls[r][c + 1] = v.y; Ls[r][c + 2] = v.z; Ls[r][c + 3] = v.w;
  }
  __syncthreads();
#pragma unroll
  for (int rr = 0; rr < 4; ++rr) {
    const int r = (t >> 4) + rr * 16, c = (t & 15) * 4;  // r: n-dim, c: k-dim
    ushort4 o;
    o.x = f2bf(Ls[c + 0][r]); o.y = f2bf(Ls[c + 1][r]);
    o.z = f2bf(Ls[c + 2][r]); o.w = f2bf(Ls[c + 3][r]);
    *(ushort4*)&Wt[(size_t)(n0 + r) * 1024 + k0 + c] = o;
  }
}

// ---------------- bf16 MFMA NT-GEMM: C[M,N] = A[M,K] @ Bt[N,K]^T + bias ----------------
template <typename OT>
__global__ __launch_bounds__(256) void gemm_bt_k(const ush* __restrict__ A,
                                                 const ush* __restrict__ Bt,
                                                 const float* __restrict__ bias,
                                                 OT* __restrict__ C,
                                                 int M, int N, int K) {
  __shared__ ush Asl[128][72];
  __shared__ ush Btl[128][72];
  const int n0 = blockIdx.x * 128;
  const int m0 = blockIdx.y * 128;
  const int tid = threadIdx.x;
  const int lane = tid & 63, w = tid >> 6;
  const int wm = (w >> 1) * 64, wn = (w & 1) * 64;
  const int ln = lane & 15, hi = lane >> 4;

  f32x4 acc[4][4] = {};
  for (int k0 = 0; k0 < K; k0 += 64) {
    __syncthreads();
#pragma unroll
    for (int rr = 0; rr < 4; ++rr) {
      const int r = (tid >> 3) + rr * 32, c = (tid & 7) * 8;
      *(ushx8*)&Asl[r][c] = *(const ushx8*)&A[(size_t)(m0 + r) * K + k0 + c];
      *(ushx8*)&Btl[r][c] = *(const ushx8*)&Bt[(size_t)(n0 + r) * K + k0 + c];
    }
    __syncthreads();
    bf16x8 af[4][2], bf[4][2];
#pragma unroll
    for (int mi = 0; mi < 4; ++mi)
#pragma unroll
      for (int ks = 0; ks < 2; ++ks)
        af[mi][ks] = *(const bf16x8*)&Asl[wm + mi * 16 + ln][ks * 32 + hi * 8];
#pragma unroll
    for (int ni = 0; ni < 4; ++ni)
#pragma unroll
      for (int ks = 0; ks < 2; ++ks)
        bf[ni][ks] = *(const bf16x8*)&Btl[wn + ni * 16 + ln][ks * 32 + hi * 8];
#pragma unroll
    for (int mi = 0; mi < 4; ++mi)
#pragma unroll
      for (int ni = 0; ni < 4; ++ni)
#pragma unroll
        for (int ks = 0; ks < 2; ++ks)
          acc[mi][ni] = __builtin_amdgcn_mfma_f32_16x16x32_bf16(
              af[mi][ks], bf[ni][ks], acc[mi][ni], 0, 0, 0);
  }
#pragma unroll
  for (int mi = 0; mi < 4; ++mi)
#pragma unroll
    for (int ni = 0; ni < 4; ++ni)
#pragma unroll
      for (int i = 0; i < 4; ++i) {
        const int grow = m0 + wm + mi * 16 + hi * 4 + i;
        const int gcol = n0 + wn + ni * 16 + ln;
        const float v = acc[mi][ni][i] + bias[gcol];
        if (sizeof(OT) == 2) {
          ((ush*)C)[(size_t)grow * N + gcol] = f2bf(v);
        } else {
          ((float*)C)[(size_t)grow * N + gcol] = v;
        }
      }
}

// ---------------- posatt MFMA ----------------
// TR=false: out[zl][q][p] (row-major).  TR=true: out[zl][p][k] transposed.
template <bool TR>
__global__ __launch_bounds__(256) void posatt_k(const ush* __restrict__ In,
                                                const ush* __restrict__ posk,
                                                ush* __restrict__ outp, int bh0) {
  __shared__ ush Al[64][72];
  __shared__ ush Bl[64][72];
  const int p0 = blockIdx.x * 64;
  const int q0 = blockIdx.y * 64;
  const int zl = blockIdx.z;
  const int bh = bh0 + zl;
  const int b = bh >> 4, h = bh & 15;
  const int tid = threadIdx.x;
  const int lane = tid & 63, w = tid >> 6;
  const int ln = lane & 15, hi = lane >> 4;

#pragma unroll
  for (int rr = 0; rr < 2; ++rr) {
    const int r = (tid >> 3) + rr * 32, c = (tid & 7) * 8;
    *(ushx8*)&Al[r][c] = *(const ushx8*)&In[(size_t)(b * SS + q0 + r) * HH + h * DD + c];
    *(ushx8*)&Bl[r][c] = *(const ushx8*)&posk[(size_t)(p0 + r) * HH + h * DD + c];
  }
  __syncthreads();

  bf16x8 aq[2];
#pragma unroll
  for (int ks = 0; ks < 2; ++ks)
    aq[ks] = *(const bf16x8*)&Al[w * 16 + ln][ks * 32 + hi * 8];
  f32x4 acc[4] = {};
#pragma unroll
  for (int ni = 0; ni < 4; ++ni)
#pragma unroll
    for (int ks = 0; ks < 2; ++ks) {
      bf16x8 bp = *(const bf16x8*)&Bl[ni * 16 + ln][ks * 32 + hi * 8];
      acc[ni] = __builtin_amdgcn_mfma_f32_16x16x32_bf16(aq[ks], bp, acc[ni], 0, 0, 0);
    }

  if (!TR) {
#pragma unroll
    for (int ni = 0; ni < 4; ++ni)
#pragma unroll
      for (int i = 0; i < 4; ++i) {
        const int orow = q0 + w * 16 + hi * 4 + i;
        const int ocol = p0 + ni * 16 + ln;
        outp[((size_t)zl * SS + orow) * SPAN2 + ocol] = f2bf(acc[ni][i]);
      }
  } else {
    __syncthreads();   // everyone done reading Al
#pragma unroll
    for (int ni = 0; ni < 4; ++ni)
#pragma unroll
      for (int i = 0; i < 4; ++i)
        Al[ni * 16 + ln][w * 16 + hi * 4 + i] = f2bf(acc[ni][i]);  // Al[p][q]
    __syncthreads();
#pragma unroll
    for (int rr = 0; rr < 2; ++rr) {
      const int r = (tid >> 3) + rr * 32, c = (tid & 7) * 8;
      *(ushx8*)&outp[((size_t)zl * SPAN2 + p0 + r) * SS + q0 + c] = *(const ushx8*)&Al[r][c];
    }
  }
}

// ---------------- MFMA flash attention with disentangled bias ----------------
// p2cT layout: [zl][p][k] (transposed) -> gather rows are near-uniform per wave.
__global__ __launch_bounds__(256) void flash_attn_k(
    const ush* __restrict__ Q, const ush* __restrict__ K, const ush* __restrict__ V,
    const ush* __restrict__ c2p, const ush* __restrict__ p2cT,
    const int* __restrict__ ctab, const int* __restrict__ ptab,
    ush* __restrict__ ctx, int bh0) {
  __shared__ ush Kl[64][72];
  __shared__ ush Vt[64][72];   // transposed: Vt[d][k]
  __shared__ ush Pl[64][72];   // also used to stage Q once
  __shared__ int ctabs[1088];
  __shared__ int ptabs[1088];

  const int q0 = blockIdx.x * 64;
  const int zl = blockIdx.y;
  const int bh = bh0 + zl;
  const int b = bh >> 4, h = bh & 15;
  const int tid = threadIdx.x;
  const int lane = tid & 63, w = tid >> 6;
  const int ln = lane & 15, hi = lane >> 4;

  for (int i2 = tid; i2 < 1087; i2 += 256) {
    ctabs[i2] = ctab[q0 + i2];
    ptabs[i2] = ptab[q0 + i2];
  }
#pragma unroll
  for (int rr = 0; rr < 2; ++rr) {
    const int r = (tid >> 3) + rr * 32, c = (tid & 7) * 8;
    *(ushx8*)&Pl[r][c] = *(const ushx8*)&Q[(size_t)(b * SS + q0 + r) * HH + h * DD + c];
  }
  __syncthreads();
  bf16x8 aq[2];
#pragma unroll
  for (int ks = 0; ks < 2; ++ks)
    aq[ks] = *(const bf16x8*)&Pl[w * 16 + ln][ks * 32 + hi * 8];
  __syncthreads();

  float m_i[4], l_i[4];
  f32x4 Oa[4] = {};
#pragma unroll
  for (int i = 0; i < 4; ++i) { m_i[i] = -1e30f; l_i[i] = 0.f; }

  const size_t zq = (size_t)zl * SS;

  for (int kt = 0; kt < 16; ++kt) {
    const int k0 = kt * 64;
    __syncthreads();
    {
#pragma unroll
      for (int rr = 0; rr < 2; ++rr) {
        const int r = (tid >> 3) + rr * 32, c = (tid & 7) * 8;
        *(ushx8*)&Kl[r][c] = *(const ushx8*)&K[(size_t)(b * SS + k0 + r) * HH + h * DD + c];
      }
      const int kp = tid & 31, dg = (tid >> 5) * 8;
      ushx8 v0 = *(const ushx8*)&V[(size_t)(b * SS + k0 + 2 * kp) * HH + h * DD + dg];
      ushx8 v1 = *(const ushx8*)&V[(size_t)(b * SS + k0 + 2 * kp + 1) * HH + h * DD + dg];
#pragma unroll
      for (int j = 0; j < 8; ++j) {
        unsigned int pk = (unsigned int)v0[j] | ((unsigned int)v1[j] << 16);
        *(unsigned int*)&Vt[dg + j][2 * kp] = pk;
      }
    }
    __syncthreads();

    // QK^T
    f32x4 s4[4] = {};
#pragma unroll
    for (int ni = 0; ni < 4; ++ni)
#pragma unroll
      for (int ks = 0; ks < 2; ++ks) {
        bf16x8 bk = *(const bf16x8*)&Kl[ni * 16 + ln][ks * 32 + hi * 8];
        s4[ni] = __builtin_amdgcn_mfma_f32_16x16x32_bf16(aq[ks], bk, s4[ni], 0, 0, 0);
      }

    // bias gathers (scores pre-scaled into log2 domain)
#pragma unroll
    for (int ni = 0; ni < 4; ++ni)
#pragma unroll
      for (int i = 0; i < 4; ++i) {
        const int qr = w * 16 + hi * 4 + i;
        const int qg = q0 + qr;
        const int kg = k0 + ni * 16 + ln;
        const int idx = qr - kg + 1023;          // in [0,1086]
        const float bias = bf2f(c2p[(zq + qg) * SPAN2 + ctabs[idx]]) +
                           bf2f(p2cT[((size_t)zl * SPAN2 + ptabs[idx]) * SS + kg]);
        s4[ni][i] = (s4[ni][i] + bias) * INV_SCALE_L2;
      }

    // online softmax in exp2 domain (rows live across 16-lane groups)
#pragma unroll
    for (int i = 0; i < 4; ++i) {
      float mx = fmaxf(fmaxf(s4[0][i], s4[1][i]), fmaxf(s4[2][i], s4[3][i]));
      mx = fmaxf(mx, __shfl_xor(mx, 1, 64));
      mx = fmaxf(mx, __shfl_xor(mx, 2, 64));
      mx = fmaxf(mx, __shfl_xor(mx, 4, 64));
      mx = fmaxf(mx, __shfl_xor(mx, 8, 64));
      const float mnew = fmaxf(m_i[i], mx);
      const float al = fast_exp2(m_i[i] - mnew);
      m_i[i] = mnew;
      float ps = 0.f;
#pragma unroll
      for (int ni = 0; ni < 4; ++ni) {
        const float p = fast_exp2(s4[ni][i] - mnew);
        s4[ni][i] = p;
        ps += p;
      }
      ps += __shfl_xor(ps, 1, 64);
      ps += __shfl_xor(ps, 2, 64);
      ps += __shfl_xor(ps, 4, 64);
      ps += __shfl_xor(ps, 8, 64);
      l_i[i] = l_i[i] * al + ps;
#pragma unroll
      for (int ni = 0; ni < 4; ++ni) Oa[ni][i] *= al;
    }

    // P -> LDS bf16
#pragma unroll
    for (int ni = 0; ni < 4; ++ni)
#pragma unroll
      for (int i = 0; i < 4; ++i)
        Pl[w * 16 + hi * 4 + i][ni * 16 + ln] = f2bf(s4[ni][i]);
    __syncthreads();

    // PV
    bf16x8 ap[2];
#pragma unroll
    for (int ks = 0; ks < 2; ++ks)
      ap[ks] = *(const bf16x8*)&Pl[w * 16 + ln][ks * 32 + hi * 8];
#pragma unroll
    for (int ni = 0; ni < 4; ++ni)
#pragma unroll
      for (int ks = 0; ks < 2; ++ks) {
        bf16x8 bv = *(const bf16x8*)&Vt[ni * 16 + ln][ks * 32 + hi * 8];
        Oa[ni] = __builtin_amdgcn_mfma_f32_16x16x32_bf16(ap[ks], bv, Oa[ni], 0, 0, 0);
      }
  }

  float inv_l[4];
#pragma unroll
  for (int i = 0; i < 4; ++i) inv_l[i] = 1.f / l_i[i];
#pragma unroll
  for (int ni = 0; ni < 4; ++ni)
#pragma unroll
    for (int i = 0; i < 4; ++i) {
      const int qg = q0 + w * 16 + hi * 4 + i;
      ctx[(size_t)(b * SS + qg) * HH + h * DD + ni * 16 + ln] = f2bf(Oa[ni][i] * inv_l[i]);
    }
}

// ---------------- residual + LayerNorm epilogue ----------------
__global__ __launch_bounds__(256) void out_ln_k(const float* __restrict__ proj,
                                                const float* __restrict__ resid,
                                                const float* __restrict__ gamma,
                                                const float* __restrict__ beta,
                                                float* __restrict__ out) {
  const int row = blockIdx.x;
  const int tid = threadIdx.x;
  const size_t base = (size_t)row * HH;
  float v[4];
  float s = 0.f;
#pragma unroll
  for (int u = 0; u < 4; ++u) {
    const int c = tid + u * 256;
    v[u] = proj[base + c] + resid[base + c];
    s += v[u];
  }
  __shared__ float red[8];
#pragma unroll
  for (int off = 32; off; off >>= 1) s += __shfl_xor(s, off, 64);
  if ((tid & 63) == 0) red[tid >> 6] = s;
  __syncthreads();
  const float mu = (red[0] + red[1] + red[2] + red[3]) * (1.f / HH);
  float s2 = 0.f;
#pragma unroll
  for (int u = 0; u < 4; ++u) { const float d = v[u] - mu; s2 += d * d; }
#pragma unroll
  for (int off = 32; off; off >>= 1) s2 += __shfl_xor(s2, off, 64);
  if ((tid & 63) == 0) red[4 + (tid >> 6)] = s2;
  __syncthreads();
  const float var = (red[4] + red[5] + red[6] + red[7]) * (1.f / HH);
  const float rs = rsqrtf(var + 1e-7f);
#pragma unroll
  for (int u = 0; u < 4; ++u) {
    const int c = tid + u * 256;
    out[base + c] = (v[u] - mu) * rs * gamma[c] + beta[c];
  }
}

extern "C" void kernel_launch(void* const* d_in, const int* in_sizes, int n_in,
                              void* d_out, int out_size, void* d_ws, size_t ws_size,
                              hipStream_t stream) {
  (void)in_sizes; (void)n_in; (void)out_size;
  const float* hs  = (const float*)d_in[0];
  const float* rel = (const float*)d_in[2];  // d_in[1] attention_mask unused (faithful)
  const float* Wq  = (const float*)d_in[3];
  const float* bq  = (const float*)d_in[4];
  const float* Wk  = (const float*)d_in[5];
  const float* bk  = (const float*)d_in[6];
  const float* Wv  = (const float*)d_in[7];
  const float* bv  = (const float*)d_in[8];
  const float* Wo  = (const float*)d_in[9];
  const float* bo  = (const float*)d_in[10];
  const float* lng = (const float*)d_in[11];
  const float* lnb = (const float*)d_in[12];
  float* out = (float*)d_out;

  // ---- workspace packing ----
  char* ws = (char*)d_ws;
  const size_t MB = 1024ull * 1024ull;
  ush*   hs_bf  = (ush*)(ws);                 //  8 MB [4096,1024]
  ush*   Q_bf   = (ush*)(ws + 8 * MB);        //  8 MB
  ush*   K_bf   = (ush*)(ws + 16 * MB);       //  8 MB
  ush*   V_bf   = (ush*)(ws + 24 * MB);       //  8 MB
  ush*   ctx_bf = (ush*)(ws + 32 * MB);       //  8 MB
  ush*   rel_bf = (ush*)(ws + 40 * MB);       //  1 MB [512,1024]
  ush*   posk_bf= (ush*)(ws + 41 * MB);       //  1 MB [512,1024]
  ush*   Wq_t   = (ush*)(ws + 42 * MB);       //  2 MB each, transposed bf16
  ush*   Wk_t   = (ush*)(ws + 44 * MB);
  ush*   Wv_t   = (ush*)(ws + 46 * MB);
  ush*   Wo_t   = (ush*)(ws + 48 * MB);
  float* proj   = (float*)(ws + 50 * MB);     // 16 MB [4096,1024] f32
  int*   ctab   = (int*)(ws + 66 * MB);       //  8 KB
  int*   ptab   = ctab + 2048;
  char*  bias_base = ws + 66 * MB + 16384;
  const size_t perbh = (size_t)SS * SPAN2 * 2;  // 1 MB per bh per buffer

  const size_t fixed = (size_t)(bias_base - ws);
  int chunk = 64;
  while (chunk > 1 && fixed + 2 * (size_t)chunk * perbh > ws_size) chunk >>= 1;
  ush* c2p  = (ush*)bias_base;
  ush* p2cT = (ush*)(bias_base + (size_t)chunk * perbh);

  build_tables_k<<<dim3(8), 256, 0, stream>>>(ctab, ptab);
  cvt_bf16_k<<<dim3(4096), 256, 0, stream>>>(hs, hs_bf);
  cvt_bf16_k<<<dim3(512), 256, 0, stream>>>(rel, rel_bf);
  transpose_cvt_k<<<dim3(16, 16), 256, 0, stream>>>(Wq, Wq_t);
  transpose_cvt_k<<<dim3(16, 16), 256, 0, stream>>>(Wk, Wk_t);
  transpose_cvt_k<<<dim3(16, 16), 256, 0, stream>>>(Wv, Wv_t);
  transpose_cvt_k<<<dim3(16, 16), 256, 0, stream>>>(Wo, Wo_t);

  gemm_bt_k<ush><<<dim3(8, 32), 256, 0, stream>>>(hs_bf, Wq_t, bq, Q_bf, 4096, 1024, 1024);
  gemm_bt_k<ush><<<dim3(8, 32), 256, 0, stream>>>(hs_bf, Wk_t, bk, K_bf, 4096, 1024, 1024);
  gemm_bt_k<ush><<<dim3(8, 32), 256, 0, stream>>>(hs_bf, Wv_t, bv, V_bf, 4096, 1024, 1024);
  gemm_bt_k<ush><<<dim3(8, 4), 256, 0, stream>>>(rel_bf, Wk_t, bk, posk_bf, 512, 1024, 1024);

  for (int bh0 = 0; bh0 < 64; bh0 += chunk) {
    posatt_k<false><<<dim3(8, 16, chunk), 256, 0, stream>>>(Q_bf, posk_bf, c2p, bh0);
    posatt_k<true><<<dim3(8, 16, chunk), 256, 0, stream>>>(K_bf, posk_bf, p2cT, bh0);
    flash_attn_k<<<dim3(16, chunk), 256, 0, stream>>>(Q_bf, K_bf, V_bf, c2p, p2cT,
                                                      ctab, ptab, ctx_bf, bh0);
  }

  gemm_bt_k<float><<<dim3(8, 32), 256, 0, stream>>>(ctx_bf, Wo_t, bo, proj, 4096, 1024, 1024);
  out_ln_k<<<4096, 256, 0, stream>>>(proj, hs, lng, lnb, out);
}